// Round 5
// baseline (655.883 us; speedup 1.0000x reference)
//
#include <hip/hip_runtime.h>
#include <hip/hip_bf16.h>

// MoE gate: logits = x(T,4096) @ W(64,4096)^T ; softmax ; group-limited top-k.
// T = 16384, E = 64, H = 4096, groups = 8x8, topk_group = 3, top_k = 6.
// Outputs concatenated in d_out (float32): idx[T*6] (float-encoded ints),
// weight[T*6], sorted descending with jax top_k tie-breaking.
//
// Round-5 == Round-4 (bench never ran: broker timeout).
// lane=token / wave=expert-group GEMM. W is read via the SCALAR pipe
// (wave-uniform addresses -> s_load_dwordx4, SGPR operands to v_fma_f32):
// zero LDS and zero VALU cost for W. x staged in LDS, ONE ds_read_b128 per
// wave per 4-k step (lane-strided rows, pitch 132 -> free 2-way aliasing).
// Split-K(2): grid 512 = 2 blocks/CU = 4 waves/SIMD. Partials -> d_ws,
// summed by the (round-3-validated) gate kernel.

#define TM     64     // tokens per block (lane = token)
#define HK     128    // K-chunk staged in LDS
#define PITCH  132    // LDS row pitch in floats
#define NE     64
#define NH     4096
#define KSPLIT 2
#define KHALF  (NH / KSPLIT)   // 2048
#define NTOPK  6

__global__ __launch_bounds__(512, 4) void moe_gemm_kernel(
    const float* __restrict__ x, const float* __restrict__ w,
    float* __restrict__ partial, int T)
{
    __shared__ float xs[TM * PITCH];   // 33.8 KB

    const int tid  = threadIdx.x;
    const int lane = tid & 63;                 // token within block
    // expert base of this wave, forced wave-uniform so W loads go scalar
    const int e0   = __builtin_amdgcn_readfirstlane((tid >> 6) << 3);
    const int blk  = blockIdx.x;
    const int t0   = (blk >> 1) * TM;          // token block
    const int kb   = (blk & 1) * KHALF;        // K half

    float acc[8];
    #pragma unroll
    for (int j = 0; j < 8; ++j) acc[j] = 0.f;

    const int c4 = (tid & 31) << 2;            // staging col (float4): 0..124
    const int r0 = tid >> 5;                   // staging row base: 0..15

    // Wave-uniform W row pointers for this wave's 8 experts.
    const float* wr[8];
    #pragma unroll
    for (int j = 0; j < 8; ++j)
        wr[j] = w + (size_t)(e0 + j) * NH + kb;

    const float* xrow = xs + lane * PITCH;

    for (int k0 = 0; k0 < KHALF; k0 += HK) {
        // ---- stage x tile (64 x 128), coalesced 512B/row ----
        #pragma unroll
        for (int p = 0; p < 4; ++p) {
            const int r = r0 + (p << 4);
            const float4 v = *reinterpret_cast<const float4*>(
                x + (size_t)(t0 + r) * NH + kb + k0 + c4);
            *reinterpret_cast<float4*>(&xs[r * PITCH + c4]) = v;
        }
        __syncthreads();

        // ---- inner: 1 ds_read_b128 + 8 scalar float4 W loads + 32 FMA ----
        #pragma unroll 8
        for (int kk = 0; kk < HK; kk += 4) {
            const float4 xa = *reinterpret_cast<const float4*>(xrow + kk);
            #pragma unroll
            for (int j = 0; j < 8; ++j) {
                const float4 wv = *reinterpret_cast<const float4*>(wr[j] + k0 + kk);
                acc[j] = fmaf(xa.x, wv.x, acc[j]);
                acc[j] = fmaf(xa.y, wv.y, acc[j]);
                acc[j] = fmaf(xa.z, wv.z, acc[j]);
                acc[j] = fmaf(xa.w, wv.w, acc[j]);
            }
        }
        __syncthreads();
    }

    // ---- write partial logits: partial[half][t][e0..e0+7] ----
    float* pbase = partial + (size_t)(blk & 1) * T * NE
                 + (size_t)(t0 + lane) * NE + e0;
    *reinterpret_cast<float4*>(pbase)     = make_float4(acc[0], acc[1], acc[2], acc[3]);
    *reinterpret_cast<float4*>(pbase + 4) = make_float4(acc[4], acc[5], acc[6], acc[7]);
}

__global__ __launch_bounds__(256, 4) void moe_gate_kernel(
    const float* __restrict__ partial,
    float* __restrict__ out_idx, float* __restrict__ out_w, int T)
{
    const int tid  = threadIdx.x;
    const int lane = tid & 63;         // lane == expert index
    const int wid  = tid >> 6;         // wave 0..3, 8 tokens each
    const int tb   = blockIdx.x * 32 + wid * 8;

    for (int tt = 0; tt < 8; ++tt) {
        const int t = tb + tt;
        const float logit = partial[(size_t)t * NE + lane]
                          + partial[(size_t)(T + t) * NE + lane];

        // softmax over 64 experts (wave-wide)
        float m = logit;
        #pragma unroll
        for (int s = 32; s > 0; s >>= 1) m = fmaxf(m, __shfl_xor(m, s));
        const float ex = expf(logit - m);
        float sum = ex;
        #pragma unroll
        for (int s = 32; s > 0; s >>= 1) sum += __shfl_xor(sum, s);
        const float score = ex / sum;

        // per-group max (groups of 8 consecutive experts)
        float gm = score;
        #pragma unroll
        for (int s = 4; s > 0; s >>= 1) gm = fmaxf(gm, __shfl_xor(gm, s));
        const int g = lane >> 3;

        // rank of this lane's group among the 8 group-maxima (stable, desc)
        int grank = 0;
        #pragma unroll
        for (int gg = 0; gg < 8; ++gg) {
            const float o = __shfl(gm, gg << 3);
            grank += (o > gm) || (o == gm && gg < g);
        }
        const float masked = (grank < 3) ? score : 0.0f;

        // rank among all 64 masked scores (stable, desc) == output position
        int rank = 0;
        for (int ee = 0; ee < 64; ++ee) {
            const float o = __shfl(masked, ee);
            rank += (o > masked) || (o == masked && ee < lane);
        }
        if (rank < NTOPK) {
            out_idx[t * NTOPK + rank] = (float)lane;   // float-encoded index
            out_w[t * NTOPK + rank]   = masked;
        }
    }
}

extern "C" void kernel_launch(void* const* d_in, const int* in_sizes, int n_in,
                              void* d_out, int out_size, void* d_ws, size_t ws_size,
                              hipStream_t stream) {
    const float* x = (const float*)d_in[0];
    const float* w = (const float*)d_in[1];
    const int T = in_sizes[0] / NH;            // 16384 tokens
    float* outf    = (float*)d_out;
    float* out_idx = outf;                     // first T*6: indices
    float* out_w   = outf + (size_t)T * NTOPK; // then  T*6: weights
    float* partial = (float*)d_ws;             // KSPLIT * T * 64 floats = 8 MB

    dim3 gg((T / TM) * KSPLIT), gb(512);       // 512 blocks x 512 threads
    hipLaunchKernelGGL(moe_gemm_kernel, gg, gb, 0, stream, x, w, partial, T);

    dim3 hg(T / 32), hb(256);                  // 512 blocks
    hipLaunchKernelGGL(moe_gate_kernel, hg, hb, 0, stream,
                       partial, out_idx, out_w, T);
}